// Round 7
// baseline (599.307 us; speedup 1.0000x reference)
//
#include <hip/hip_runtime.h>
#include <hip/hip_bf16.h>

// Problem constants
#define MROW 8192   // BATCH
#define DIMK 4096   // DIM (= K of both GEMMs)
#define NCOL 4096   // N_HEADS*HIDDEN = DIM
#define HID  256
#define NH   16
#define SEQL 4096

// GEMM: 256x256 tile, BK=32, 8 waves (2M x 4N, wave-tile 128x64), 16x16x32 MFMA,
// ring-of-4 LDS slots (A 16KB + B 16KB each = 128KB), phase-pipelined reads.
#define BKT 32
#define NKT (DIMK / BKT)       // 128 K-tiles
#define SLOTB 32768
#define LDS_TOTAL (4 * SLOTB)  // 131072

typedef __attribute__((ext_vector_type(8))) short short8;
typedef __attribute__((ext_vector_type(4))) float f32x4;

__device__ inline ushort f2bf(float f) {
  unsigned u = __float_as_uint(f);
  u += 0x7FFF + ((u >> 16) & 1);   // RNE
  return (ushort)(u >> 16);
}

__device__ inline void gload16(const void* g, void* l) {
  __builtin_amdgcn_global_load_lds(
      (const __attribute__((address_space(1))) void*)g,
      (__attribute__((address_space(3))) void*)l, 16, 0, 0);
}

// fp32 -> bf16, 8 elements/thread, grid-stride
__global__ void cvt_f32_bf16(const float* __restrict__ s, ushort* __restrict__ d, long n8) {
  long stride = (long)gridDim.x * blockDim.x;
  for (long i = (long)blockIdx.x * blockDim.x + threadIdx.x; i < n8; i += stride) {
    const float4* s4 = (const float4*)(s + i * 8);
    float4 a = s4[0], b = s4[1];
    ushort r[8] = {f2bf(a.x), f2bf(a.y), f2bf(a.z), f2bf(a.w),
                   f2bf(b.x), f2bf(b.y), f2bf(b.z), f2bf(b.w)};
    *(uint4*)(d + i * 8) = *(const uint4*)r;
  }
}

// per-output-column coefficients for the GEMM1 epilogue
__global__ void coef_kernel(const float* __restrict__ mix_w, const float* __restrict__ mix_b,
                            const float* __restrict__ decay_value, const float* __restrict__ proj_b,
                            const int* __restrict__ index_p,
                            float* __restrict__ wv, float* __restrict__ cc, float* __restrict__ pb2) {
  int n = blockIdx.x * blockDim.x + threadIdx.x;   // 0..4095
  if (n >= NCOL) return;
  int h = n >> 8;
  int idx = *index_p;
  float w  = mix_w[h * SEQL + idx];
  float bb = mix_b[h * SEQL + idx];
  float dv = fminf(fmaxf(decay_value[h], 0.9f), 1.0f);
  float decay = powf(dv, 0.125f);                  // 1/DECAY_CONSTANT (=8)
  float coef = (h < NH / 2) ? w * decay : decay;
  wv[n]  = w;
  cc[n]  = coef;
  pb2[n] = w * proj_b[n] + bb;
}

// C = A(MxK)*B^T(NxK), bf16. Phase-pipelined: every ds_read's consumer is one
// full MFMA cluster (16) later, so LDS latency hides under the matrix pipe.
// Swizzle: 16B slot = c ^ ((row>>1)&3) (measured 0 conflicts), inverse on the
// global source (linear LDS dest for global_load_lds), forward on reads.
template <int EPI>
__global__ __launch_bounds__(512, 2) void gemmp(
    const ushort* __restrict__ A, const ushort* __restrict__ B,
    float* __restrict__ outf, ushort* __restrict__ outh,
    const float* __restrict__ cache, const float* __restrict__ wv,
    const float* __restrict__ cc, const float* __restrict__ pb2,
    const float* __restrict__ outb) {
  extern __shared__ __align__(16) char smem[];

  const int tid  = threadIdx.x;
  const int lane = tid & 63;
  const int wid  = tid >> 6;      // 0..7
  const int wr = wid >> 2;        // 0..1 (M)  wave-tile 128 rows
  const int wc = wid & 3;         // 0..3 (N)  wave-tile 64 cols
  const int r16 = lane & 15;
  const int cq  = lane >> 4;

  // XCD swizzle (grid 512, bijective)
  const int bid = blockIdx.x;
  const int swz = (bid & 7) * 64 + (bid >> 3);
  const int bm = swz >> 4, bn = swz & 15;   // 32 x 16 tiles
  const int m0 = bm * 256, n0 = bn * 256;

  const ushort* Ag = A + (size_t)m0 * DIMK;
  const ushort* Bg = B + (size_t)n0 * DIMK;

  // ---- precomputed LDS read byte-offsets (loop-invariant; swizzled)
  int aoff[8], boff[4];
#pragma unroll
  for (int i = 0; i < 8; ++i) {
    int arow = wr * 128 + i * 16 + r16;
    aoff[i] = arow * 64 + ((cq ^ ((arow >> 1) & 3)) << 4);
  }
#pragma unroll
  for (int i = 0; i < 4; ++i) {
    int brow = wc * 64 + i * 16 + r16;
    boff[i] = 16384 + brow * 64 + ((cq ^ ((brow >> 1) & 3)) << 4);
  }

  // ---- precomputed stage offsets: linear LDS dest, inverse-swizzled global src
  int soff[2], sgo[2];
#pragma unroll
  for (int j = 0; j < 2; ++j) {
    int off = j * 8192 + tid * 16;           // [0, 16384)
    int row = off >> 6;
    soff[j] = off;
    sgo[j]  = row * DIMK + ((((off >> 4) & 3) ^ ((row >> 1) & 3)) << 3);
  }

  f32x4 acc[8][4] = {};

  // prologue: stage K-tiles 0..2 (A+B = 4 gloads each)
#pragma unroll
  for (int kt = 0; kt < 3; ++kt) {
    char* s = smem + kt * SLOTB;
#pragma unroll
    for (int j = 0; j < 2; ++j) {
      gload16(Ag + (size_t)sgo[j] + kt * BKT, s + soff[j]);
      gload16(Bg + (size_t)sgo[j] + kt * BKT, s + 16384 + soff[j]);
    }
  }
  asm volatile("s_waitcnt vmcnt(4)" ::: "memory");   // kt0,kt1 landed
  __builtin_amdgcn_s_barrier();
  __builtin_amdgcn_sched_barrier(0);

  // preload frags for kt=0
  short8 blo[4], alo[4];
#pragma unroll
  for (int i = 0; i < 4; ++i) blo[i] = *(const short8*)(smem + boff[i]);
#pragma unroll
  for (int i = 0; i < 4; ++i) alo[i] = *(const short8*)(smem + aoff[i]);

  for (int kt = 0; kt < NKT; ++kt) {
    const char* cur = smem + (kt & 3) * SLOTB;
    const char* nxt = smem + ((kt + 1) & 3) * SLOTB;
    char*       st  = smem + ((kt + 3) & 3) * SLOTB;   // == slot (kt-1)&3
    const bool  do_st = kt < NKT - 3;
    const int   k3 = (kt + 3) * BKT;

    // ---- phase 0: issue A-high(kt) reads + stage A(kt+3); MFMA on A-low(kt)
    short8 ahi[4];
#pragma unroll
    for (int i = 0; i < 4; ++i) ahi[i] = *(const short8*)(cur + aoff[4 + i]);
    if (do_st) {
      gload16(Ag + (size_t)sgo[0] + k3, st + soff[0]);
      gload16(Ag + (size_t)sgo[1] + k3, st + soff[1]);
    }
    __builtin_amdgcn_sched_barrier(0);
    __builtin_amdgcn_s_setprio(1);
#pragma unroll
    for (int mi = 0; mi < 4; ++mi)
#pragma unroll
      for (int ni = 0; ni < 4; ++ni)
        acc[mi][ni] = __builtin_amdgcn_mfma_f32_16x16x32_bf16(alo[mi], blo[ni], acc[mi][ni], 0, 0, 0);
    __builtin_amdgcn_s_setprio(0);

    // ---- phase 1: issue B(kt+1)+A-low(kt+1) reads + stage B(kt+3); MFMA on A-high(kt)
    short8 bn[4], an[4];
    if (kt < NKT - 1) {
#pragma unroll
      for (int i = 0; i < 4; ++i) bn[i] = *(const short8*)(nxt + boff[i]);
#pragma unroll
      for (int i = 0; i < 4; ++i) an[i] = *(const short8*)(nxt + aoff[i]);
    }
    if (do_st) {
      gload16(Bg + (size_t)sgo[0] + k3, st + 16384 + soff[0]);
      gload16(Bg + (size_t)sgo[1] + k3, st + 16384 + soff[1]);
    }
    __builtin_amdgcn_sched_barrier(0);
    __builtin_amdgcn_s_setprio(1);
#pragma unroll
    for (int mi = 0; mi < 4; ++mi)
#pragma unroll
      for (int ni = 0; ni < 4; ++ni)
        acc[4 + mi][ni] = __builtin_amdgcn_mfma_f32_16x16x32_bf16(ahi[mi], blo[ni], acc[4 + mi][ni], 0, 0, 0);
    __builtin_amdgcn_s_setprio(0);

    // counted wait (never 0 in steady state): kt+2 fully landed, kt+3 in flight
    if (kt < NKT - 3)       asm volatile("s_waitcnt vmcnt(4)" ::: "memory");
    else if (kt == NKT - 3) asm volatile("s_waitcnt vmcnt(0)" ::: "memory");
    __builtin_amdgcn_s_barrier();
    // LOAD-BEARING fence: next iteration's stage targets the slot read THIS
    // iteration — must not hoist above the barrier.
    __builtin_amdgcn_sched_barrier(0);

#pragma unroll
    for (int i = 0; i < 4; ++i) { blo[i] = bn[i]; alo[i] = an[i]; }
  }

  // ---- epilogue. C/D 16x16 map: col = lane&15, row = (lane>>4)*4 + reg
  const int colb = n0 + wc * 64 + r16;
  const int rowb = m0 + wr * 128 + cq * 4;

  float wvv[4], ccv[4], pbv[4], obv[4];
#pragma unroll
  for (int ni = 0; ni < 4; ++ni) {
    int n = colb + ni * 16;
    if (EPI == 1) { wvv[ni] = wv[n]; ccv[ni] = cc[n]; pbv[ni] = pb2[n]; }
    else          { obv[ni] = outb[n]; }
  }

#pragma unroll
  for (int am = 0; am < 8; ++am) {
    int mrow = rowb + am * 16;
#pragma unroll
    for (int ni = 0; ni < 4; ++ni) {
      f32x4 v = acc[am][ni];
      int n = colb + ni * 16;
#pragma unroll
      for (int r = 0; r < 4; ++r) {
        int m = mrow + r;
        if (EPI == 1) {
          int h = n >> 8, kq = n & 255;
          float val = wvv[ni] * v[r] + ccv[ni] * cache[((size_t)h * MROW + m) * HID + kq] + pbv[ni];
          outh[(size_t)m * NCOL + n] = f2bf(val);
        } else {
          outf[(size_t)m * NCOL + n] = v[r] + obv[ni];
        }
      }
    }
  }
}

extern "C" void kernel_launch(void* const* d_in, const int* in_sizes, int n_in,
                              void* d_out, int out_size, void* d_ws, size_t ws_size,
                              hipStream_t stream) {
  const float* x      = (const float*)d_in[0];
  const float* proj_w = (const float*)d_in[1];
  const float* proj_b = (const float*)d_in[2];
  const float* mix_w  = (const float*)d_in[3];
  const float* mix_b  = (const float*)d_in[4];
  const float* decay  = (const float*)d_in[5];
  const float* cache  = (const float*)d_in[6];
  const float* out_w  = (const float*)d_in[7];
  const float* out_b  = (const float*)d_in[8];
  const int*   index  = (const int*)d_in[9];

  char* ws = (char*)d_ws;
  ushort* xb  = (ushort*)ws;                         // 64 MiB
  ushort* pwb = (ushort*)(ws + 67108864);            // 32 MiB
  ushort* owb = (ushort*)(ws + 100663296);           // 32 MiB
  ushort* hid = (ushort*)(ws + 134217728);           // 64 MiB
  float*  wv  = (float*)(ws + 201326592);
  float*  cc  = (float*)(ws + 201326592 + 16384);
  float*  pb2 = (float*)(ws + 201326592 + 32768);

  hipFuncSetAttribute((const void*)&gemmp<1>, hipFuncAttributeMaxDynamicSharedMemorySize, LDS_TOTAL);
  hipFuncSetAttribute((const void*)&gemmp<0>, hipFuncAttributeMaxDynamicSharedMemorySize, LDS_TOTAL);

  hipLaunchKernelGGL(cvt_f32_bf16, dim3(2048), dim3(256), 0, stream,
                     x, xb, (long)MROW * DIMK / 8);
  hipLaunchKernelGGL(cvt_f32_bf16, dim3(1024), dim3(256), 0, stream,
                     proj_w, pwb, (long)NCOL * DIMK / 8);
  hipLaunchKernelGGL(cvt_f32_bf16, dim3(1024), dim3(256), 0, stream,
                     out_w, owb, (long)NCOL * DIMK / 8);
  hipLaunchKernelGGL(coef_kernel, dim3(16), dim3(256), 0, stream,
                     mix_w, mix_b, decay, proj_b, index, wv, cc, pb2);

  // GEMM1: hidden = mix(x @ proj_w^T) -> bf16
  hipLaunchKernelGGL((gemmp<1>), dim3((MROW / 256) * (NCOL / 256)), dim3(512), LDS_TOTAL, stream,
                     xb, pwb, nullptr, hid, cache, wv, cc, pb2, nullptr);
  // GEMM2: out = hidden @ out_w^T + out_b -> f32
  hipLaunchKernelGGL((gemmp<0>), dim3((MROW / 256) * (NCOL / 256)), dim3(512), LDS_TOTAL, stream,
                     hid, owb, (float*)d_out, nullptr, nullptr, nullptr, nullptr, nullptr, out_b);
}

// Round 8
// 597.747 us; speedup vs baseline: 1.0026x; 1.0026x over previous
//
#include <hip/hip_runtime.h>
#include <hip/hip_bf16.h>

// Problem constants
#define MROW 8192   // BATCH
#define DIMK 4096   // DIM (= K of both GEMMs)
#define NCOL 4096   // N_HEADS*HIDDEN = DIM
#define HID  256
#define NH   16
#define SEQL 4096

// GEMM tile geometry: 256x256 tile, BK=32, 16 waves (4M x 4N, wave-tile 64x64),
// ring-of-4 LDS (4 x 32KB = 128KB), one 1024-thread block per CU.
#define BKT 32
#define NKT (DIMK / BKT)       // 128 K-tiles
#define SLOTB 32768            // ring slot: A 16KB + B 16KB
#define LDS_TOTAL (4 * SLOTB)  // 131072

typedef __attribute__((ext_vector_type(8))) short short8;
typedef __attribute__((ext_vector_type(4))) float f32x4;

// RAW barrier: inline asm so the compiler CANNOT attach its implicit
// s_waitcnt vmcnt(0) drain (which would kill the counted-vmcnt prefetch
// pipeline every iteration). Producer ordering is enforced by the explicit
// counted vmcnt asm before each barrier.
#define SBAR() asm volatile("s_barrier" ::: "memory")

__device__ inline ushort f2bf(float f) {
  unsigned u = __float_as_uint(f);
  u += 0x7FFF + ((u >> 16) & 1);   // RNE
  return (ushort)(u >> 16);
}

__device__ inline void gload16(const void* g, void* l) {
  __builtin_amdgcn_global_load_lds(
      (const __attribute__((address_space(1))) void*)g,
      (__attribute__((address_space(3))) void*)l, 16, 0, 0);
}

// fp32 -> bf16, 8 elements/thread, grid-stride
__global__ void cvt_f32_bf16(const float* __restrict__ s, ushort* __restrict__ d, long n8) {
  long stride = (long)gridDim.x * blockDim.x;
  for (long i = (long)blockIdx.x * blockDim.x + threadIdx.x; i < n8; i += stride) {
    const float4* s4 = (const float4*)(s + i * 8);
    float4 a = s4[0], b = s4[1];
    ushort r[8] = {f2bf(a.x), f2bf(a.y), f2bf(a.z), f2bf(a.w),
                   f2bf(b.x), f2bf(b.y), f2bf(b.z), f2bf(b.w)};
    *(uint4*)(d + i * 8) = *(const uint4*)r;
  }
}

// per-output-column coefficients for the GEMM1 epilogue
__global__ void coef_kernel(const float* __restrict__ mix_w, const float* __restrict__ mix_b,
                            const float* __restrict__ decay_value, const float* __restrict__ proj_b,
                            const int* __restrict__ index_p,
                            float* __restrict__ wv, float* __restrict__ cc, float* __restrict__ pb2) {
  int n = blockIdx.x * blockDim.x + threadIdx.x;   // 0..4095
  if (n >= NCOL) return;
  int h = n >> 8;
  int idx = *index_p;
  float w  = mix_w[h * SEQL + idx];
  float bb = mix_b[h * SEQL + idx];
  float dv = fminf(fmaxf(decay_value[h], 0.9f), 1.0f);
  float decay = powf(dv, 0.125f);                  // 1/DECAY_CONSTANT (=8)
  float coef = (h < NH / 2) ? w * decay : decay;
  wv[n]  = w;
  cc[n]  = coef;
  pb2[n] = w * proj_b[n] + bb;
}

// C = A(MxK)*B^T(NxK), bf16, 16x16x32 MFMA. LDS tile row = 64B (32 bf16),
// swizzle: 16B slot = c ^ ((row>>1)&3) (measured 0 conflicts), applied
// inversely on the global source (linear LDS dest), forward on reads.
// 16 waves, one RAW barrier per K-tile, counted vmcnt (never 0 in steady
// state — prefetches stay in flight ACROSS barriers), ring-of-4.
template <int EPI>
__global__ __launch_bounds__(1024, 4) void gemm256(
    const ushort* __restrict__ A, const ushort* __restrict__ B,
    float* __restrict__ outf, ushort* __restrict__ outh,
    const float* __restrict__ cache, const float* __restrict__ wv,
    const float* __restrict__ cc, const float* __restrict__ pb2,
    const float* __restrict__ outb) {
  extern __shared__ __align__(16) char smem[];

  const int tid  = threadIdx.x;
  const int lane = tid & 63;
  const int wid  = tid >> 6;      // 0..15
  const int wr = wid >> 2;        // 0..3 (M)
  const int wc = wid & 3;         // 0..3 (N)
  const int r16 = lane & 15;
  const int cq  = lane >> 4;      // 16B column block 0..3

  // XCD swizzle (grid 512, bijective)
  const int bid = blockIdx.x;
  const int swz = (bid & 7) * 64 + (bid >> 3);
  const int bm = swz >> 4, bn = swz & 15;   // 32 x 16 tiles
  const int m0 = bm * 256, n0 = bn * 256;

  const ushort* Ag = A + (size_t)m0 * DIMK;
  const ushort* Bg = B + (size_t)n0 * DIMK;

  // ---- precomputed LDS read byte-offsets (loop-invariant; swizzled)
  int aoff[4], boff[4];
#pragma unroll
  for (int i = 0; i < 4; ++i) {
    int arow = wr * 64 + i * 16 + r16;
    aoff[i] = arow * 64 + ((cq ^ ((arow >> 1) & 3)) << 4);
    int brow = wc * 64 + i * 16 + r16;
    boff[i] = 16384 + brow * 64 + ((cq ^ ((brow >> 1) & 3)) << 4);
  }

  // ---- precomputed stage offsets: linear LDS dest, inverse-swizzled global src
  const int soff = tid * 16;                 // [0, 16384)
  const int srow = soff >> 6;
  const int sgo  = srow * DIMK + ((((soff >> 4) & 3) ^ ((srow >> 1) & 3)) << 3);

  f32x4 acc[4][4] = {};

  // prologue: stage K-tiles 0..2 into ring slots 0..2 (2 loads per thread per kt)
#pragma unroll
  for (int kt = 0; kt < 3; ++kt) {
    char* s = smem + kt * SLOTB;
    gload16(Ag + (size_t)sgo + kt * BKT, s + soff);
    gload16(Bg + (size_t)sgo + kt * BKT, s + 16384 + soff);
  }
  asm volatile("s_waitcnt vmcnt(4)" ::: "memory");   // kt0 landed
  SBAR();

  for (int kt = 0; kt < NKT; ++kt) {
    const char* cur = smem + (kt & 3) * SLOTB;

    short8 af[4], bf[4];
#pragma unroll
    for (int i = 0; i < 4; ++i) bf[i] = *(const short8*)(cur + boff[i]);
#pragma unroll
    for (int i = 0; i < 4; ++i) af[i] = *(const short8*)(cur + aoff[i]);

    // prefetch K-tile kt+3 into ring slot (kt+3)&3 (= (kt-1)&3, consumed last iter)
    if (kt < NKT - 3) {
      char* st = smem + ((kt + 3) & 3) * SLOTB;
      int k0 = (kt + 3) * BKT;
      gload16(Ag + (size_t)sgo + k0, st + soff);
      gload16(Bg + (size_t)sgo + k0, st + 16384 + soff);
    }

    __builtin_amdgcn_s_setprio(1);
#pragma unroll
    for (int mi = 0; mi < 4; ++mi)
#pragma unroll
      for (int ni = 0; ni < 4; ++ni)
        acc[mi][ni] = __builtin_amdgcn_mfma_f32_16x16x32_bf16(af[mi], bf[ni], acc[mi][ni], 0, 0, 0);
    __builtin_amdgcn_s_setprio(0);

    // counted wait: guarantee kt+1 landed; deeper prefetch stays in flight
    // ACROSS the barrier (never drains to 0 in steady state).
    if (kt < NKT - 3)       asm volatile("s_waitcnt vmcnt(4)" ::: "memory");
    else if (kt == NKT - 3) asm volatile("s_waitcnt vmcnt(2)" ::: "memory");
    else if (kt == NKT - 2) asm volatile("s_waitcnt vmcnt(0)" ::: "memory");
    SBAR();
  }

  // ---- epilogue. C/D 16x16 map: col = lane&15, row = (lane>>4)*4 + reg
  const int colb = n0 + wc * 64 + r16;
  const int rowb = m0 + wr * 64 + cq * 4;

  float wvv[4], ccv[4], pbv[4], obv[4];
#pragma unroll
  for (int ni = 0; ni < 4; ++ni) {
    int n = colb + ni * 16;
    if (EPI == 1) { wvv[ni] = wv[n]; ccv[ni] = cc[n]; pbv[ni] = pb2[n]; }
    else          { obv[ni] = outb[n]; }
  }

#pragma unroll
  for (int mi = 0; mi < 4; ++mi) {
#pragma unroll
    for (int ni = 0; ni < 4; ++ni) {
      f32x4 v = acc[mi][ni];
      int n = colb + ni * 16;
#pragma unroll
      for (int r = 0; r < 4; ++r) {
        int m = rowb + mi * 16 + r;
        if (EPI == 1) {
          int h = n >> 8, kq = n & 255;
          float val = wvv[ni] * v[r] + ccv[ni] * cache[((size_t)h * MROW + m) * HID + kq] + pbv[ni];
          outh[(size_t)m * NCOL + n] = f2bf(val);
        } else {
          outf[(size_t)m * NCOL + n] = v[r] + obv[ni];
        }
      }
    }
  }
}

extern "C" void kernel_launch(void* const* d_in, const int* in_sizes, int n_in,
                              void* d_out, int out_size, void* d_ws, size_t ws_size,
                              hipStream_t stream) {
  const float* x      = (const float*)d_in[0];
  const float* proj_w = (const float*)d_in[1];
  const float* proj_b = (const float*)d_in[2];
  const float* mix_w  = (const float*)d_in[3];
  const float* mix_b  = (const float*)d_in[4];
  const float* decay  = (const float*)d_in[5];
  const float* cache  = (const float*)d_in[6];
  const float* out_w  = (const float*)d_in[7];
  const float* out_b  = (const float*)d_in[8];
  const int*   index  = (const int*)d_in[9];

  char* ws = (char*)d_ws;
  ushort* xb  = (ushort*)ws;                         // 64 MiB
  ushort* pwb = (ushort*)(ws + 67108864);            // 32 MiB
  ushort* owb = (ushort*)(ws + 100663296);           // 32 MiB
  ushort* hid = (ushort*)(ws + 134217728);           // 64 MiB
  float*  wv  = (float*)(ws + 201326592);
  float*  cc  = (float*)(ws + 201326592 + 16384);
  float*  pb2 = (float*)(ws + 201326592 + 32768);

  hipFuncSetAttribute((const void*)&gemm256<1>, hipFuncAttributeMaxDynamicSharedMemorySize, LDS_TOTAL);
  hipFuncSetAttribute((const void*)&gemm256<0>, hipFuncAttributeMaxDynamicSharedMemorySize, LDS_TOTAL);

  hipLaunchKernelGGL(cvt_f32_bf16, dim3(2048), dim3(256), 0, stream,
                     x, xb, (long)MROW * DIMK / 8);
  hipLaunchKernelGGL(cvt_f32_bf16, dim3(1024), dim3(256), 0, stream,
                     proj_w, pwb, (long)NCOL * DIMK / 8);
  hipLaunchKernelGGL(cvt_f32_bf16, dim3(1024), dim3(256), 0, stream,
                     out_w, owb, (long)NCOL * DIMK / 8);
  hipLaunchKernelGGL(coef_kernel, dim3(16), dim3(256), 0, stream,
                     mix_w, mix_b, decay, proj_b, index, wv, cc, pb2);

  // GEMM1: hidden = mix(x @ proj_w^T) -> bf16
  hipLaunchKernelGGL((gemm256<1>), dim3((MROW / 256) * (NCOL / 256)), dim3(1024), LDS_TOTAL, stream,
                     xb, pwb, nullptr, hid, cache, wv, cc, pb2, nullptr);
  // GEMM2: out = hidden @ out_w^T + out_b -> f32
  hipLaunchKernelGGL((gemm256<0>), dim3((MROW / 256) * (NCOL / 256)), dim3(1024), LDS_TOTAL, stream,
                     hid, owb, (float*)d_out, nullptr, nullptr, nullptr, nullptr, nullptr, out_b);
}

// Round 9
// 590.998 us; speedup vs baseline: 1.0141x; 1.0114x over previous
//
#include <hip/hip_runtime.h>
#include <hip/hip_bf16.h>

// Problem constants
#define MROW 8192   // BATCH
#define DIMK 4096   // DIM (= K of both GEMMs)
#define NCOL 4096   // N_HEADS*HIDDEN = DIM
#define HID  256
#define NH   16
#define SEQL 4096

// GEMM: 256x256 tile, BK=32, 8 waves (2M x 4N, wave-tile 128x64), 16x16x32 MFMA,
// ring-of-4 LDS slots (A 16KB + B 16KB = 32KB each, 128KB total), m201-style
// barrier-pair phases: 4 phases per 2-K-tile iteration, 16 MFMA per phase,
// vmcnt counted at phases 2 and 4 only.
#define BKT 32
#define NKT (DIMK / BKT)       // 128 K-tiles
#define NIT (NKT / 2)          // 64 iterations
#define SLOTB 32768
#define LDS_TOTAL (4 * SLOTB)  // 131072

typedef __attribute__((ext_vector_type(8))) short short8;
typedef __attribute__((ext_vector_type(4))) float f32x4;

#define BAR() __builtin_amdgcn_s_barrier()
#define LG0() asm volatile("s_waitcnt lgkmcnt(0)" ::: "memory")

__device__ inline ushort f2bf(float f) {
  unsigned u = __float_as_uint(f);
  u += 0x7FFF + ((u >> 16) & 1);   // RNE
  return (ushort)(u >> 16);
}

__device__ inline void gload16(const void* g, void* l) {
  __builtin_amdgcn_global_load_lds(
      (const __attribute__((address_space(1))) void*)g,
      (__attribute__((address_space(3))) void*)l, 16, 0, 0);
}

// fp32 -> bf16, 8 elements/thread, grid-stride
__global__ void cvt_f32_bf16(const float* __restrict__ s, ushort* __restrict__ d, long n8) {
  long stride = (long)gridDim.x * blockDim.x;
  for (long i = (long)blockIdx.x * blockDim.x + threadIdx.x; i < n8; i += stride) {
    const float4* s4 = (const float4*)(s + i * 8);
    float4 a = s4[0], b = s4[1];
    ushort r[8] = {f2bf(a.x), f2bf(a.y), f2bf(a.z), f2bf(a.w),
                   f2bf(b.x), f2bf(b.y), f2bf(b.z), f2bf(b.w)};
    *(uint4*)(d + i * 8) = *(const uint4*)r;
  }
}

// per-output-column coefficients for the GEMM1 epilogue
__global__ void coef_kernel(const float* __restrict__ mix_w, const float* __restrict__ mix_b,
                            const float* __restrict__ decay_value, const float* __restrict__ proj_b,
                            const int* __restrict__ index_p,
                            float* __restrict__ wv, float* __restrict__ cc, float* __restrict__ pb2) {
  int n = blockIdx.x * blockDim.x + threadIdx.x;   // 0..4095
  if (n >= NCOL) return;
  int h = n >> 8;
  int idx = *index_p;
  float w  = mix_w[h * SEQL + idx];
  float bb = mix_b[h * SEQL + idx];
  float dv = fminf(fmaxf(decay_value[h], 0.9f), 1.0f);
  float decay = powf(dv, 0.125f);                  // 1/DECAY_CONSTANT (=8)
  float coef = (h < NH / 2) ? w * decay : decay;
  wv[n]  = w;
  cc[n]  = coef;
  pb2[n] = w * proj_b[n] + bb;
}

// C = A(MxK)*B^T(NxK), bf16. m201 phase template: per phase {issue 4-8 ds_read +
// 2 global_load_lds -> s_barrier -> lgkmcnt(0) -> setprio(1) 16xMFMA setprio(0)
// -> [counted vmcnt] -> s_barrier}. Prefetch stays in flight across barriers.
// Swizzle: 16B slot = c ^ ((row>>1)&3) (measured 0 conflicts), inverse on the
// global source (linear LDS dest for global_load_lds), forward on reads.
template <int EPI>
__global__ __launch_bounds__(512, 2) void gemm8p(
    const ushort* __restrict__ A, const ushort* __restrict__ B,
    float* __restrict__ outf, ushort* __restrict__ outh,
    const float* __restrict__ cache, const float* __restrict__ wv,
    const float* __restrict__ cc, const float* __restrict__ pb2,
    const float* __restrict__ outb) {
  extern __shared__ __align__(16) char smem[];

  const int tid  = threadIdx.x;
  const int lane = tid & 63;
  const int wid  = tid >> 6;      // 0..7
  const int wr = wid >> 2;        // 0..1 (M): wave rows = wr*128 .. +127
  const int wc = wid & 3;         // 0..3 (N): wave cols = wc*64 .. +63
  const int r16 = lane & 15;
  const int cq  = lane >> 4;

  // XCD swizzle (grid 512, bijective)
  const int bid = blockIdx.x;
  const int swz = (bid & 7) * 64 + (bid >> 3);
  const int bm = swz >> 4, bn = swz & 15;   // 32 x 16 tiles
  const int m0 = bm * 256, n0 = bn * 256;

  const ushort* Ag = A + (size_t)m0 * DIMK;
  const ushort* Bg = B + (size_t)n0 * DIMK;

  // ---- precomputed LDS read byte-offsets (loop-invariant; swizzled)
  int aoff0[4], aoff1[4], boff[4];
#pragma unroll
  for (int i = 0; i < 4; ++i) {
    int r0 = wr * 128 + i * 16 + r16;              // A-low half rows
    aoff0[i] = r0 * 64 + ((cq ^ ((r0 >> 1) & 3)) << 4);
    int r1 = r0 + 64;                              // A-high half rows
    aoff1[i] = r1 * 64 + ((cq ^ ((r1 >> 1) & 3)) << 4);
    int rb = wc * 64 + i * 16 + r16;
    boff[i] = 16384 + rb * 64 + ((cq ^ ((rb >> 1) & 3)) << 4);
  }

  // ---- precomputed stage offsets: linear LDS dest, inverse-swizzled global src
  int soff[2], sgo[2];
#pragma unroll
  for (int j = 0; j < 2; ++j) {
    int off = j * 8192 + tid * 16;                 // [0, 16384)
    int row = off >> 6;
    soff[j] = off;
    sgo[j]  = row * DIMK + ((((off >> 4) & 3) ^ ((row >> 1) & 3)) << 3);
  }

  f32x4 acc[8][4] = {};

  // prologue: stage K-tiles 0..2 into slots 0..2 (A then B, 4 loads per tile)
#pragma unroll
  for (int kt = 0; kt < 3; ++kt) {
    char* s = smem + kt * SLOTB;
#pragma unroll
    for (int j = 0; j < 2; ++j) gload16(Ag + (size_t)sgo[j] + kt * BKT, s + soff[j]);
#pragma unroll
    for (int j = 0; j < 2; ++j) gload16(Bg + (size_t)sgo[j] + kt * BKT, s + 16384 + soff[j]);
  }
  asm volatile("s_waitcnt vmcnt(8)" ::: "memory");   // tile 0 landed
  BAR();

  for (int it = 0; it < NIT; ++it) {
    const int kt = it * 2;
    const char* s0 = smem + (kt & 3) * SLOTB;
    const char* s1 = smem + ((kt + 1) & 3) * SLOTB;
    char* st1 = smem + ((kt + 3) & 3) * SLOTB;   // slot of tile kt-1 (consumed prev iter)
    char* st2 = smem + (kt & 3) * SLOTB;         // re-stage s0 for tile kt+4
    const bool do1 = (kt + 3) < NKT, do2 = (kt + 4) < NKT;
    const size_t k1 = (size_t)(kt + 3) * BKT, k2 = (size_t)(kt + 4) * BKT;

    short8 af[4], bf[4];

    // ---- phase 1: reads B(kt)+A-lo(kt); stage A(kt+3); MFMA acc[0..3]
#pragma unroll
    for (int i = 0; i < 4; ++i) bf[i] = *(const short8*)(s0 + boff[i]);
#pragma unroll
    for (int i = 0; i < 4; ++i) af[i] = *(const short8*)(s0 + aoff0[i]);
    if (do1) { gload16(Ag + sgo[0] + k1, st1 + soff[0]); gload16(Ag + sgo[1] + k1, st1 + soff[1]); }
    BAR(); LG0();
    __builtin_amdgcn_s_setprio(1);
#pragma unroll
    for (int mi = 0; mi < 4; ++mi)
#pragma unroll
      for (int ni = 0; ni < 4; ++ni)
        acc[mi][ni] = __builtin_amdgcn_mfma_f32_16x16x32_bf16(af[mi], bf[ni], acc[mi][ni], 0, 0, 0);
    __builtin_amdgcn_s_setprio(0);
    BAR();

    // ---- phase 2: reads A-hi(kt); stage B(kt+3); MFMA acc[4..7]; vmcnt
#pragma unroll
    for (int i = 0; i < 4; ++i) af[i] = *(const short8*)(s0 + aoff1[i]);
    if (do1) { gload16(Bg + sgo[0] + k1, st1 + 16384 + soff[0]); gload16(Bg + sgo[1] + k1, st1 + 16384 + soff[1]); }
    BAR(); LG0();
    __builtin_amdgcn_s_setprio(1);
#pragma unroll
    for (int mi = 0; mi < 4; ++mi)
#pragma unroll
      for (int ni = 0; ni < 4; ++ni)
        acc[4 + mi][ni] = __builtin_amdgcn_mfma_f32_16x16x32_bf16(af[mi], bf[ni], acc[4 + mi][ni], 0, 0, 0);
    __builtin_amdgcn_s_setprio(0);
    if (it < NIT - 1) asm volatile("s_waitcnt vmcnt(8)" ::: "memory");   // tile kt+1 landed
    else              asm volatile("s_waitcnt vmcnt(0)" ::: "memory");
    BAR();

    // ---- phase 3: reads B(kt+1)+A-lo(kt+1); stage A(kt+4) -> s0 (safe: s0 drained); MFMA acc[0..3]
#pragma unroll
    for (int i = 0; i < 4; ++i) bf[i] = *(const short8*)(s1 + boff[i]);
#pragma unroll
    for (int i = 0; i < 4; ++i) af[i] = *(const short8*)(s1 + aoff0[i]);
    if (do2) { gload16(Ag + sgo[0] + k2, st2 + soff[0]); gload16(Ag + sgo[1] + k2, st2 + soff[1]); }
    BAR(); LG0();
    __builtin_amdgcn_s_setprio(1);
#pragma unroll
    for (int mi = 0; mi < 4; ++mi)
#pragma unroll
      for (int ni = 0; ni < 4; ++ni)
        acc[mi][ni] = __builtin_amdgcn_mfma_f32_16x16x32_bf16(af[mi], bf[ni], acc[mi][ni], 0, 0, 0);
    __builtin_amdgcn_s_setprio(0);
    BAR();

    // ---- phase 4: reads A-hi(kt+1); stage B(kt+4); MFMA acc[4..7]; vmcnt
#pragma unroll
    for (int i = 0; i < 4; ++i) af[i] = *(const short8*)(s1 + aoff1[i]);
    if (do2) { gload16(Bg + sgo[0] + k2, st2 + 16384 + soff[0]); gload16(Bg + sgo[1] + k2, st2 + 16384 + soff[1]); }
    BAR(); LG0();
    __builtin_amdgcn_s_setprio(1);
#pragma unroll
    for (int mi = 0; mi < 4; ++mi)
#pragma unroll
      for (int ni = 0; ni < 4; ++ni)
        acc[4 + mi][ni] = __builtin_amdgcn_mfma_f32_16x16x32_bf16(af[mi], bf[ni], acc[4 + mi][ni], 0, 0, 0);
    __builtin_amdgcn_s_setprio(0);
    if (it < NIT - 2)       asm volatile("s_waitcnt vmcnt(8)" ::: "memory");  // tile kt+2 landed
    else if (it == NIT - 2) asm volatile("s_waitcnt vmcnt(4)" ::: "memory");
    BAR();
  }

  // ---- epilogue. C/D 16x16 map: col = lane&15, row = (lane>>4)*4 + reg
  const int colb = n0 + wc * 64 + r16;
  const int rowb = m0 + wr * 128 + cq * 4;

  float wvv[4], ccv[4], pbv[4], obv[4];
#pragma unroll
  for (int ni = 0; ni < 4; ++ni) {
    int n = colb + ni * 16;
    if (EPI == 1) { wvv[ni] = wv[n]; ccv[ni] = cc[n]; pbv[ni] = pb2[n]; }
    else          { obv[ni] = outb[n]; }
  }

#pragma unroll
  for (int am = 0; am < 8; ++am) {
    int mrow = rowb + am * 16;
#pragma unroll
    for (int ni = 0; ni < 4; ++ni) {
      f32x4 v = acc[am][ni];
      int n = colb + ni * 16;
#pragma unroll
      for (int r = 0; r < 4; ++r) {
        int m = mrow + r;
        if (EPI == 1) {
          int h = n >> 8, kq = n & 255;
          float val = wvv[ni] * v[r] + ccv[ni] * cache[((size_t)h * MROW + m) * HID + kq] + pbv[ni];
          outh[(size_t)m * NCOL + n] = f2bf(val);
        } else {
          outf[(size_t)m * NCOL + n] = v[r] + obv[ni];
        }
      }
    }
  }
}

extern "C" void kernel_launch(void* const* d_in, const int* in_sizes, int n_in,
                              void* d_out, int out_size, void* d_ws, size_t ws_size,
                              hipStream_t stream) {
  const float* x      = (const float*)d_in[0];
  const float* proj_w = (const float*)d_in[1];
  const float* proj_b = (const float*)d_in[2];
  const float* mix_w  = (const float*)d_in[3];
  const float* mix_b  = (const float*)d_in[4];
  const float* decay  = (const float*)d_in[5];
  const float* cache  = (const float*)d_in[6];
  const float* out_w  = (const float*)d_in[7];
  const float* out_b  = (const float*)d_in[8];
  const int*   index  = (const int*)d_in[9];

  char* ws = (char*)d_ws;
  ushort* xb  = (ushort*)ws;                         // 64 MiB
  ushort* pwb = (ushort*)(ws + 67108864);            // 32 MiB
  ushort* owb = (ushort*)(ws + 100663296);           // 32 MiB
  ushort* hid = (ushort*)(ws + 134217728);           // 64 MiB
  float*  wv  = (float*)(ws + 201326592);
  float*  cc  = (float*)(ws + 201326592 + 16384);
  float*  pb2 = (float*)(ws + 201326592 + 32768);

  hipFuncSetAttribute((const void*)&gemm8p<1>, hipFuncAttributeMaxDynamicSharedMemorySize, LDS_TOTAL);
  hipFuncSetAttribute((const void*)&gemm8p<0>, hipFuncAttributeMaxDynamicSharedMemorySize, LDS_TOTAL);

  hipLaunchKernelGGL(cvt_f32_bf16, dim3(2048), dim3(256), 0, stream,
                     x, xb, (long)MROW * DIMK / 8);
  hipLaunchKernelGGL(cvt_f32_bf16, dim3(1024), dim3(256), 0, stream,
                     proj_w, pwb, (long)NCOL * DIMK / 8);
  hipLaunchKernelGGL(cvt_f32_bf16, dim3(1024), dim3(256), 0, stream,
                     out_w, owb, (long)NCOL * DIMK / 8);
  hipLaunchKernelGGL(coef_kernel, dim3(16), dim3(256), 0, stream,
                     mix_w, mix_b, decay, proj_b, index, wv, cc, pb2);

  // GEMM1: hidden = mix(x @ proj_w^T) -> bf16
  hipLaunchKernelGGL((gemm8p<1>), dim3((MROW / 256) * (NCOL / 256)), dim3(512), LDS_TOTAL, stream,
                     xb, pwb, nullptr, hid, cache, wv, cc, pb2, nullptr);
  // GEMM2: out = hidden @ out_w^T + out_b -> f32
  hipLaunchKernelGGL((gemm8p<0>), dim3((MROW / 256) * (NCOL / 256)), dim3(512), LDS_TOTAL, stream,
                     hid, owb, (float*)d_out, nullptr, nullptr, nullptr, nullptr, nullptr, out_b);
}

// Round 10
// 587.073 us; speedup vs baseline: 1.0208x; 1.0067x over previous
//
#include <hip/hip_runtime.h>
#include <hip/hip_bf16.h>

// Problem constants
#define MROW 8192   // BATCH
#define DIMK 4096   // DIM (= K of both GEMMs)
#define NCOL 4096   // N_HEADS*HIDDEN = DIM
#define HID  256
#define NH   16
#define SEQL 4096

// GEMM: 256x256 tile, BK=64, 8 waves (2M x 4N, wave-tile 128x64), 16x16x32 MFMA,
// double-buffered LDS (2 x 64KB), one barrier per K-tile, depth-1 prefetch with
// vmcnt(0) at iteration end (~2500 cyc cover >> HBM latency).
#define BKT 64
#define NKT (DIMK / BKT)       // 64 K-tiles
#define SLOTB 65536            // A 32KB + B 32KB
#define LDS_TOTAL (2 * SLOTB)  // 131072

typedef __attribute__((ext_vector_type(8))) short short8;
typedef __attribute__((ext_vector_type(4))) float f32x4;

#define SBAR() asm volatile("s_barrier" ::: "memory")

__device__ inline ushort f2bf(float f) {
  unsigned u = __float_as_uint(f);
  u += 0x7FFF + ((u >> 16) & 1);   // RNE
  return (ushort)(u >> 16);
}

__device__ inline void gload16(const void* g, void* l) {
  __builtin_amdgcn_global_load_lds(
      (const __attribute__((address_space(1))) void*)g,
      (__attribute__((address_space(3))) void*)l, 16, 0, 0);
}

// fp32 -> bf16, 8 elements/thread, grid-stride
__global__ void cvt_f32_bf16(const float* __restrict__ s, ushort* __restrict__ d, long n8) {
  long stride = (long)gridDim.x * blockDim.x;
  for (long i = (long)blockIdx.x * blockDim.x + threadIdx.x; i < n8; i += stride) {
    const float4* s4 = (const float4*)(s + i * 8);
    float4 a = s4[0], b = s4[1];
    ushort r[8] = {f2bf(a.x), f2bf(a.y), f2bf(a.z), f2bf(a.w),
                   f2bf(b.x), f2bf(b.y), f2bf(b.z), f2bf(b.w)};
    *(uint4*)(d + i * 8) = *(const uint4*)r;
  }
}

// per-output-column coefficients for the GEMM1 epilogue
__global__ void coef_kernel(const float* __restrict__ mix_w, const float* __restrict__ mix_b,
                            const float* __restrict__ decay_value, const float* __restrict__ proj_b,
                            const int* __restrict__ index_p,
                            float* __restrict__ wv, float* __restrict__ cc, float* __restrict__ pb2) {
  int n = blockIdx.x * blockDim.x + threadIdx.x;   // 0..4095
  if (n >= NCOL) return;
  int h = n >> 8;
  int idx = *index_p;
  float w  = mix_w[h * SEQL + idx];
  float bb = mix_b[h * SEQL + idx];
  float dv = fminf(fmaxf(decay_value[h], 0.9f), 1.0f);
  float decay = powf(dv, 0.125f);                  // 1/DECAY_CONSTANT (=8)
  float coef = (h < NH / 2) ? w * decay : decay;
  wv[n]  = w;
  cc[n]  = coef;
  pb2[n] = w * proj_b[n] + bb;
}

// C = A(MxK)*B^T(NxK), bf16, BK=64. LDS row = 128B (64 bf16, 8 x 16B slots);
// swizzle: slot' = slot ^ (row&7) — conflict-free on frag reads (uniform
// 8 accesses/bank/wave), full-128B-line coalesced on the (inverse-swizzled)
// global staging source. Depth-1 dbuf: stage kt+1 at iter start, vmcnt(0) at
// iter end, one barrier per K-tile. EPI==1: mix -> bf16; EPI==0: +out_b -> f32.
template <int EPI>
__global__ __launch_bounds__(512, 2) void gemmk64(
    const ushort* __restrict__ A, const ushort* __restrict__ B,
    float* __restrict__ outf, ushort* __restrict__ outh,
    const float* __restrict__ cache, const float* __restrict__ wv,
    const float* __restrict__ cc, const float* __restrict__ pb2,
    const float* __restrict__ outb) {
  extern __shared__ __align__(16) char smem[];

  const int tid  = threadIdx.x;
  const int lane = tid & 63;
  const int wid  = tid >> 6;      // 0..7
  const int wr = wid >> 2;        // 0..1 (M): rows wr*128..+127
  const int wc = wid & 3;         // 0..3 (N): cols wc*64..+63
  const int r16 = lane & 15;
  const int cq  = lane >> 4;      // 0..3

  // XCD swizzle (grid 512, bijective)
  const int bid = blockIdx.x;
  const int swz = (bid & 7) * 64 + (bid >> 3);
  const int bm = swz >> 4, bn = swz & 15;   // 32 x 16 tiles
  const int m0 = bm * 256, n0 = bn * 256;

  const ushort* Ag = A + (size_t)m0 * DIMK;
  const ushort* Bg = B + (size_t)n0 * DIMK;

  // ---- frag read bases (loop-invariant). byte(row, ks) =
  //      row*128 + ((ks*4+cq) ^ (row&7))*16 ; row&7 == r16&7 for all frags.
  const int ax0 = ((0 * 4 + cq) ^ (r16 & 7)) << 4;
  const int ax1 = ((1 * 4 + cq) ^ (r16 & 7)) << 4;
  const int abase = (wr * 128 + r16) * 128;            // A region starts at 0
  const int bbase = 32768 + (wc * 64 + r16) * 128;     // B region
  // ds_read addresses = base + i*2048 (folded into offset: immediates)

  // ---- stage addressing: per thread 8 granules of 16B.
  // LDS dest (linear): tid*16 + g*8192  (A: region [0,32768), B: +32768)
  // global src: row = tid>>3 (+64 per g), slot = tid&7; elem = row*DIMK + (slot^(row&7))*8
  const int srow = tid >> 3;                 // 0..63
  const int sgo  = srow * DIMK + (((tid & 7) ^ (srow & 7)) << 3);   // elements
  const int ldst = tid * 16;                 // bytes

  f32x4 acc[8][4] = {};

  // prologue: stage tile 0 into slot 0
#pragma unroll
  for (int g = 0; g < 4; ++g) {
    gload16(Ag + (size_t)sgo + (size_t)g * 64 * DIMK, smem + ldst + g * 8192);
    gload16(Bg + (size_t)sgo + (size_t)g * 64 * DIMK, smem + 32768 + ldst + g * 8192);
  }
  asm volatile("s_waitcnt vmcnt(0)" ::: "memory");
  SBAR();
  __builtin_amdgcn_sched_barrier(0);

  for (int kt = 0; kt < NKT; ++kt) {
    const char* cur = smem + (kt & 1) * SLOTB;
    const bool  do_st = kt + 1 < NKT;

    // ---- stage tile kt+1 into the other slot (its previous contents were
    // fully consumed before the barrier ending iteration kt-1)
    if (do_st) {
      char* st = smem + ((kt + 1) & 1) * SLOTB;
      const size_t k0 = (size_t)(kt + 1) * BKT;
#pragma unroll
      for (int g = 0; g < 4; ++g) {
        gload16(Ag + (size_t)sgo + (size_t)g * 64 * DIMK + k0, st + ldst + g * 8192);
        gload16(Bg + (size_t)sgo + (size_t)g * 64 * DIMK + k0, st + 32768 + ldst + g * 8192);
      }
    }

    // ---- k-slice 0: reads + 32 MFMA
    {
      short8 af[8], bf[4];
#pragma unroll
      for (int i = 0; i < 8; ++i) af[i] = *(const short8*)(cur + abase + ax0 + i * 2048);
#pragma unroll
      for (int i = 0; i < 4; ++i) bf[i] = *(const short8*)(cur + bbase + ax0 + i * 2048);
      __builtin_amdgcn_s_setprio(1);
#pragma unroll
      for (int mi = 0; mi < 8; ++mi)
#pragma unroll
        for (int ni = 0; ni < 4; ++ni)
          acc[mi][ni] = __builtin_amdgcn_mfma_f32_16x16x32_bf16(af[mi], bf[ni], acc[mi][ni], 0, 0, 0);
      __builtin_amdgcn_s_setprio(0);
    }
    // ---- k-slice 1: reads + 32 MFMA
    {
      short8 af[8], bf[4];
#pragma unroll
      for (int i = 0; i < 8; ++i) af[i] = *(const short8*)(cur + abase + ax1 + i * 2048);
#pragma unroll
      for (int i = 0; i < 4; ++i) bf[i] = *(const short8*)(cur + bbase + ax1 + i * 2048);
      __builtin_amdgcn_s_setprio(1);
#pragma unroll
      for (int mi = 0; mi < 8; ++mi)
#pragma unroll
        for (int ni = 0; ni < 4; ++ni)
          acc[mi][ni] = __builtin_amdgcn_mfma_f32_16x16x32_bf16(af[mi], bf[ni], acc[mi][ni], 0, 0, 0);
      __builtin_amdgcn_s_setprio(0);
    }

    // tile kt+1 must be fully landed before anyone reads it next iteration.
    if (do_st) asm volatile("s_waitcnt vmcnt(0)" ::: "memory");
    asm volatile("s_waitcnt lgkmcnt(0)" ::: "memory");
    SBAR();
    __builtin_amdgcn_sched_barrier(0);
  }

  // ---- epilogue. C/D 16x16 map: col = lane&15, row = (lane>>4)*4 + reg
  const int colb = n0 + wc * 64 + r16;
  const int rowb = m0 + wr * 128 + cq * 4;

  float wvv[4], ccv[4], pbv[4], obv[4];
#pragma unroll
  for (int ni = 0; ni < 4; ++ni) {
    int n = colb + ni * 16;
    if (EPI == 1) { wvv[ni] = wv[n]; ccv[ni] = cc[n]; pbv[ni] = pb2[n]; }
    else          { obv[ni] = outb[n]; }
  }

#pragma unroll
  for (int am = 0; am < 8; ++am) {
    int mrow = rowb + am * 16;
#pragma unroll
    for (int ni = 0; ni < 4; ++ni) {
      f32x4 v = acc[am][ni];
      int n = colb + ni * 16;
#pragma unroll
      for (int r = 0; r < 4; ++r) {
        int m = mrow + r;
        if (EPI == 1) {
          int h = n >> 8, kq = n & 255;
          float val = wvv[ni] * v[r] + ccv[ni] * cache[((size_t)h * MROW + m) * HID + kq] + pbv[ni];
          outh[(size_t)m * NCOL + n] = f2bf(val);
        } else {
          outf[(size_t)m * NCOL + n] = v[r] + obv[ni];
        }
      }
    }
  }
}

extern "C" void kernel_launch(void* const* d_in, const int* in_sizes, int n_in,
                              void* d_out, int out_size, void* d_ws, size_t ws_size,
                              hipStream_t stream) {
  const float* x      = (const float*)d_in[0];
  const float* proj_w = (const float*)d_in[1];
  const float* proj_b = (const float*)d_in[2];
  const float* mix_w  = (const float*)d_in[3];
  const float* mix_b  = (const float*)d_in[4];
  const float* decay  = (const float*)d_in[5];
  const float* cache  = (const float*)d_in[6];
  const float* out_w  = (const float*)d_in[7];
  const float* out_b  = (const float*)d_in[8];
  const int*   index  = (const int*)d_in[9];

  char* ws = (char*)d_ws;
  ushort* xb  = (ushort*)ws;                         // 64 MiB
  ushort* pwb = (ushort*)(ws + 67108864);            // 32 MiB
  ushort* owb = (ushort*)(ws + 100663296);           // 32 MiB
  ushort* hid = (ushort*)(ws + 134217728);           // 64 MiB
  float*  wv  = (float*)(ws + 201326592);
  float*  cc  = (float*)(ws + 201326592 + 16384);
  float*  pb2 = (float*)(ws + 201326592 + 32768);

  hipFuncSetAttribute((const void*)&gemmk64<1>, hipFuncAttributeMaxDynamicSharedMemorySize, LDS_TOTAL);
  hipFuncSetAttribute((const void*)&gemmk64<0>, hipFuncAttributeMaxDynamicSharedMemorySize, LDS_TOTAL);

  hipLaunchKernelGGL(cvt_f32_bf16, dim3(2048), dim3(256), 0, stream,
                     x, xb, (long)MROW * DIMK / 8);
  hipLaunchKernelGGL(cvt_f32_bf16, dim3(1024), dim3(256), 0, stream,
                     proj_w, pwb, (long)NCOL * DIMK / 8);
  hipLaunchKernelGGL(cvt_f32_bf16, dim3(1024), dim3(256), 0, stream,
                     out_w, owb, (long)NCOL * DIMK / 8);
  hipLaunchKernelGGL(coef_kernel, dim3(16), dim3(256), 0, stream,
                     mix_w, mix_b, decay, proj_b, index, wv, cc, pb2);

  // GEMM1: hidden = mix(x @ proj_w^T) -> bf16
  hipLaunchKernelGGL((gemmk64<1>), dim3((MROW / 256) * (NCOL / 256)), dim3(512), LDS_TOTAL, stream,
                     xb, pwb, nullptr, hid, cache, wv, cc, pb2, nullptr);
  // GEMM2: out = hidden @ out_w^T + out_b -> f32
  hipLaunchKernelGGL((gemmk64<0>), dim3((MROW / 256) * (NCOL / 256)), dim3(512), LDS_TOTAL, stream,
                     hid, owb, (float*)d_out, nullptr, nullptr, nullptr, nullptr, nullptr, out_b);
}